// Round 8
// baseline (808.937 us; speedup 1.0000x reference)
//
#include <hip/hip_runtime.h>

// Masked scatter-mean, 4-kernel pipeline (no float atomics anywhere).
// R7b: non-temporal hints on all stream-once traffic (edge inputs, pairs,
// csr reads, out stores) so the 256MB Infinity Cache keeps feat (256MB)
// resident across its ~3.7x reuse; feat loads remain cacheable.
// (R7 fix: nt store needs a clang ext_vector_type, not HIP float4.)
//   init_bcur  : bcur[b] = b*CAP
//   bin_fixed  : ONE edge pass (load+hist merged); reserve ranges; write
//                packed (src<<10 | tgt&1023) into per-bucket windows [nt]
//   csr_build  : per-bucket LDS hist+scan; in-place sort of window [nt]
//   gather_reduce : 8 lanes/target; predicated 8-deep gather pipeline;
//                nt csr loads, cached feat loads, nt out stores
// Fallback: R1 atomic path if ws too small / shapes out of range.

#define CCH 32
#define BSH 10            // 1024 targets per bucket
#define BKT 1024
#define CAP 14336         // slots per bucket window (mean fill ~7345)
#define BIN_TILE 8192
typedef unsigned int u32;
typedef float f32x4 __attribute__((ext_vector_type(4)));

__global__ __launch_bounds__(256) void init_bcur_kernel(u32* __restrict__ bcur,
                                                        int NB) {
  int i = blockIdx.x * 256 + threadIdx.x;
  if (i < NB) bcur[i] = (u32)i * (u32)CAP;
}

__global__ __launch_bounds__(1024) void bin_fixed_kernel(
    const int* __restrict__ src_ids, const int* __restrict__ tgt_ids,
    const int* __restrict__ ntypes, u32* __restrict__ bcur,
    u32* __restrict__ pairs, int E, int NB) {
  __shared__ unsigned short s_b[BIN_TILE];  // bucket id (0xFFFF = invalid)
  __shared__ u32 s_pw[BIN_TILE];            // packed (src<<10 | local_tgt)
  __shared__ u32 s_cnt[2048];
  __shared__ u32 s_base[2048];
  const long long base = (long long)blockIdx.x * BIN_TILE;

  for (int j = threadIdx.x; j < 2048; j += 1024) s_cnt[j] = 0;
  __syncthreads();

  // merged load + histogram pass
  for (int k = 0; k < BIN_TILE / 1024; ++k) {
    const int i = threadIdx.x + k * 1024;
    const long long e = base + i;
    unsigned short bb = 0xFFFFu;
    u32 pw = 0;
    if (e < E) {
      const long long eb = 3LL * e;
      const int n0 = __builtin_nontemporal_load(&ntypes[eb]);
      const int n1 = __builtin_nontemporal_load(&ntypes[eb + 1]);
      const int n2 = __builtin_nontemporal_load(&ntypes[eb + 2]);
      if ((n0 | n1 | n2) >= 0) {
        const u32 t = (u32)__builtin_nontemporal_load(&tgt_ids[e]);
        const u32 s = (u32)__builtin_nontemporal_load(&src_ids[e]);
        bb = (unsigned short)(t >> BSH);
        pw = (s << BSH) | (t & (BKT - 1u));
        atomicAdd(&s_cnt[bb], 1u);
      }
    }
    s_b[i] = bb;
    s_pw[i] = pw;
  }
  __syncthreads();

  for (int j = threadIdx.x; j < NB; j += 1024) {
    const u32 c = s_cnt[j];
    s_base[j] = c ? atomicAdd(&bcur[j], c) : 0u;
    s_cnt[j] = 0;
  }
  __syncthreads();

  for (int k = 0; k < BIN_TILE / 1024; ++k) {
    const int i = threadIdx.x + k * 1024;
    const unsigned short bb = s_b[i];
    if (bb != 0xFFFFu) {
      const u32 loc = atomicAdd(&s_cnt[bb], 1u);
      const u32 slot = s_base[bb] + loc;
      if (slot < ((u32)bb + 1u) * (u32)CAP)
        __builtin_nontemporal_store(s_pw[i], &pairs[slot]);  // clamp
    }
  }
}

__global__ __launch_bounds__(1024) void csr_build_kernel(
    u32* __restrict__ pairs, const u32* __restrict__ bcur,
    u32* __restrict__ offsets, int n_tgt) {
  __shared__ u32 s_pw[CAP];   // 56 KB staged window
  __shared__ u32 s_cnt[BKT];  // hist, then scatter cursors
  __shared__ u32 s_off[BKT];  // inclusive scan
  const int b = blockIdx.x;
  const u32 wbeg = (u32)b * (u32)CAP;
  u32 fill = bcur[b] - wbeg;
  if (fill > (u32)CAP) fill = (u32)CAP;

  for (u32 i = threadIdx.x; i < fill; i += 1024)
    s_pw[i] = __builtin_nontemporal_load(&pairs[wbeg + i]);
  s_cnt[threadIdx.x] = 0;  // blockDim == BKT
  __syncthreads();
  for (u32 i = threadIdx.x; i < fill; i += 1024)
    atomicAdd(&s_cnt[s_pw[i] & (BKT - 1u)], 1u);
  __syncthreads();

  const u32 v = s_cnt[threadIdx.x];
  s_off[threadIdx.x] = v;
  __syncthreads();
  for (int d = 1; d < BKT; d <<= 1) {
    const u32 add = (threadIdx.x >= (unsigned)d) ? s_off[threadIdx.x - d] : 0u;
    __syncthreads();
    s_off[threadIdx.x] += add;
    __syncthreads();
  }
  const u32 excl = s_off[threadIdx.x] - v;

  const int t0 = b << BSH;
  if (t0 + (int)threadIdx.x < n_tgt)
    __builtin_nontemporal_store((v << 16) | excl, &offsets[t0 + threadIdx.x]);

  s_cnt[threadIdx.x] = excl;  // scatter cursors
  __syncthreads();
  for (u32 i = threadIdx.x; i < fill; i += 1024) {
    const u32 pw = s_pw[i];
    const u32 loc = atomicAdd(&s_cnt[pw & (BKT - 1u)], 1u);
    __builtin_nontemporal_store(pw >> BSH, &pairs[wbeg + loc]);  // in-place CSR
  }
}

__global__ __launch_bounds__(256) void gather_reduce_kernel(
    const float* __restrict__ feat, const u32* __restrict__ csr,
    const u32* __restrict__ offsets, float* __restrict__ out, int n_tgt) {
  const int tid = blockIdx.x * 256 + threadIdx.x;
  const int t = tid >> 3;
  const int g = tid & 7;
  if (t >= n_tgt) return;
  const u32 off = __builtin_nontemporal_load(&offsets[t]);
  const u32 n = off >> 16;
  const u32 base = ((u32)(t >> BSH)) * (u32)CAP + (off & 0xFFFFu);
  const int l4 = g * 4;

  f32x4 acc = {0.f, 0.f, 0.f, 0.f};
  for (u32 c = 0; c < n; c += 8) {
    const u32 m = n - c;  // >= 1
    u32 idx[8];
#pragma unroll
    for (int k = 0; k < 8; ++k)
      idx[k] = __builtin_nontemporal_load(
          &csr[base + c + ((u32)k < m ? (u32)k : 0u)]);
    f32x4 v[8];
#pragma unroll
    for (int k = 0; k < 8; ++k)
      v[k] = *reinterpret_cast<const f32x4*>(feat +
                                             (long long)idx[k] * CCH + l4);
#pragma unroll
    for (int k = 0; k < 8; ++k) {
      const float w = ((u32)k < m) ? 1.0f : 0.0f;
      acc += v[k] * w;
    }
  }
  const float inv = n ? 1.0f / (float)n : 0.0f;
  const f32x4 r = acc * inv;
  __builtin_nontemporal_store(
      r, reinterpret_cast<f32x4*>(out + (long long)t * CCH + l4));
}

// ---------------- fallback: R1 atomic path ----------------

__global__ __launch_bounds__(256) void scatter_accum_kernel(
    const float* __restrict__ feat, const int* __restrict__ src_ids,
    const int* __restrict__ tgt_ids, const int* __restrict__ ntypes,
    float* __restrict__ sums, u32* __restrict__ counts,
    long long total_threads) {
  long long tid = (long long)blockIdx.x * blockDim.x + threadIdx.x;
  if (tid >= total_threads) return;
  const int e = (int)(tid >> 3);
  const int g = (int)(tid & 7);
  const long long eb = 3LL * e;
  if ((ntypes[eb] | ntypes[eb + 1] | ntypes[eb + 2]) < 0) return;
  const int s = src_ids[e];
  const int t = tgt_ids[e];
  const float4 v =
      *reinterpret_cast<const float4*>(feat + (long long)s * CCH + g * 4);
  float* dst = sums + (long long)t * CCH + g * 4;
  atomicAdd(dst + 0, v.x);
  atomicAdd(dst + 1, v.y);
  atomicAdd(dst + 2, v.z);
  atomicAdd(dst + 3, v.w);
  if (g == 0) atomicAdd(counts + t, 1u);
}

__global__ __launch_bounds__(256) void finalize_kernel(
    float* __restrict__ out, const u32* __restrict__ counts, int total_vec4) {
  int tid = blockIdx.x * blockDim.x + threadIdx.x;
  if (tid >= total_vec4) return;
  const int t = tid >> 3;
  const u32 cnt = counts[t];
  float4* p = reinterpret_cast<float4*>(out) + tid;
  float4 v = *p;
  const float inv = (cnt > 0u) ? (1.0f / (float)cnt) : 0.0f;
  v.x *= inv; v.y *= inv; v.z *= inv; v.w *= inv;
  *p = v;
}

// ---------------- launch ----------------

extern "C" void kernel_launch(void* const* d_in, const int* in_sizes, int n_in,
                              void* d_out, int out_size, void* d_ws,
                              size_t ws_size, hipStream_t stream) {
  const float* feat    = (const float*)d_in[0];
  const int*   src_ids = (const int*)d_in[1];
  const int*   tgt_ids = (const int*)d_in[2];
  const int*   ntypes  = (const int*)d_in[3];
  const int E     = in_sizes[1];
  const int n_src = in_sizes[0] / CCH;
  const int n_tgt = out_size / CCH;

  const int NB = (n_tgt + BKT - 1) >> BSH;

  // ws layout (u32): pairs/csr windows [NB*CAP] | bcur[NB] | offsets[n_tgt]
  const size_t need =
      ((size_t)NB * CAP + NB + (size_t)n_tgt) * sizeof(u32);
  const bool shapes_ok =
      NB <= 2048 && n_src <= (1 << 22) &&
      (long long)E <= (long long)NB * CAP * 3 / 4;  // fill margin

  if (ws_size >= need && shapes_ok) {
    u32* pairs   = (u32*)d_ws;
    u32* bcur    = pairs + (size_t)NB * CAP;
    u32* offsets = bcur + NB;

    init_bcur_kernel<<<(NB + 255) / 256, 256, 0, stream>>>(bcur, NB);
    const int bblocks = (E + BIN_TILE - 1) / BIN_TILE;
    bin_fixed_kernel<<<bblocks, 1024, 0, stream>>>(src_ids, tgt_ids, ntypes,
                                                   bcur, pairs, E, NB);
    csr_build_kernel<<<NB, 1024, 0, stream>>>(pairs, bcur, offsets, n_tgt);
    const long long gthreads = (long long)n_tgt * 8;
    const int gblocks = (int)((gthreads + 255) / 256);
    gather_reduce_kernel<<<gblocks, 256, 0, stream>>>(feat, pairs, offsets,
                                                      (float*)d_out, n_tgt);
  } else {
    float* sums   = (float*)d_out;
    u32*   counts = (u32*)d_ws;
    hipMemsetAsync(d_out, 0, (size_t)out_size * sizeof(float), stream);
    hipMemsetAsync(d_ws, 0, (size_t)n_tgt * sizeof(u32), stream);
    const long long total_threads = (long long)E * 8;
    const long long nblocks = (total_threads + 255) / 256;
    scatter_accum_kernel<<<(dim3)((unsigned int)nblocks), 256, 0, stream>>>(
        feat, src_ids, tgt_ids, ntypes, sums, counts, total_threads);
    const int total_vec4 = n_tgt * 8;
    finalize_kernel<<<(total_vec4 + 255) / 256, 256, 0, stream>>>(
        sums, counts, total_vec4);
  }
}

// Round 9
// 294.605 us; speedup vs baseline: 2.7458x; 2.7458x over previous
//
#include <hip/hip_runtime.h>

// Masked scatter-mean, 4-kernel pipeline (no float atomics anywhere).
// R9: nt hints ONLY on streaming loads (edge inputs, csr/offset reads) and
// the full-line out store. All scattered stores are plain cached stores —
// R8 showed scattered 4B nt stores bypass L2 write-coalescing (10x write
// amplification, bin_fixed 70->360us).
//   init_bcur  : bcur[b] = b*CAP
//   bin_fixed  : ONE edge pass (load+hist merged, nt loads); reserve ranges;
//                plain cached scattered writes of packed (src<<10|tgt&1023)
//   csr_build  : per-bucket LDS hist+scan; in-place sort (plain lds/sts)
//   gather_reduce : 8 lanes/target; predicated 8-deep gather pipeline;
//                nt csr/offset loads, cached feat loads, nt full-line out store
// Fallback: R1 atomic path if ws too small / shapes out of range.

#define CCH 32
#define BSH 10            // 1024 targets per bucket
#define BKT 1024
#define CAP 14336         // slots per bucket window (mean fill ~7345)
#define BIN_TILE 8192
typedef unsigned int u32;
typedef float f32x4 __attribute__((ext_vector_type(4)));

__global__ __launch_bounds__(256) void init_bcur_kernel(u32* __restrict__ bcur,
                                                        int NB) {
  int i = blockIdx.x * 256 + threadIdx.x;
  if (i < NB) bcur[i] = (u32)i * (u32)CAP;
}

__global__ __launch_bounds__(1024) void bin_fixed_kernel(
    const int* __restrict__ src_ids, const int* __restrict__ tgt_ids,
    const int* __restrict__ ntypes, u32* __restrict__ bcur,
    u32* __restrict__ pairs, int E, int NB) {
  __shared__ unsigned short s_b[BIN_TILE];  // bucket id (0xFFFF = invalid)
  __shared__ u32 s_pw[BIN_TILE];            // packed (src<<10 | local_tgt)
  __shared__ u32 s_cnt[2048];
  __shared__ u32 s_base[2048];
  const long long base = (long long)blockIdx.x * BIN_TILE;

  for (int j = threadIdx.x; j < 2048; j += 1024) s_cnt[j] = 0;
  __syncthreads();

  // merged load + histogram pass (nt loads: stream-once edge data)
  for (int k = 0; k < BIN_TILE / 1024; ++k) {
    const int i = threadIdx.x + k * 1024;
    const long long e = base + i;
    unsigned short bb = 0xFFFFu;
    u32 pw = 0;
    if (e < E) {
      const long long eb = 3LL * e;
      const int n0 = __builtin_nontemporal_load(&ntypes[eb]);
      const int n1 = __builtin_nontemporal_load(&ntypes[eb + 1]);
      const int n2 = __builtin_nontemporal_load(&ntypes[eb + 2]);
      if ((n0 | n1 | n2) >= 0) {
        const u32 t = (u32)__builtin_nontemporal_load(&tgt_ids[e]);
        const u32 s = (u32)__builtin_nontemporal_load(&src_ids[e]);
        bb = (unsigned short)(t >> BSH);
        pw = (s << BSH) | (t & (BKT - 1u));
        atomicAdd(&s_cnt[bb], 1u);
      }
    }
    s_b[i] = bb;
    s_pw[i] = pw;
  }
  __syncthreads();

  for (int j = threadIdx.x; j < NB; j += 1024) {
    const u32 c = s_cnt[j];
    s_base[j] = c ? atomicAdd(&bcur[j], c) : 0u;
    s_cnt[j] = 0;
  }
  __syncthreads();

  for (int k = 0; k < BIN_TILE / 1024; ++k) {
    const int i = threadIdx.x + k * 1024;
    const unsigned short bb = s_b[i];
    if (bb != 0xFFFFu) {
      const u32 loc = atomicAdd(&s_cnt[bb], 1u);
      const u32 slot = s_base[bb] + loc;
      if (slot < ((u32)bb + 1u) * (u32)CAP) pairs[slot] = s_pw[i];  // cached
    }
  }
}

__global__ __launch_bounds__(1024) void csr_build_kernel(
    u32* __restrict__ pairs, const u32* __restrict__ bcur,
    u32* __restrict__ offsets, int n_tgt) {
  __shared__ u32 s_pw[CAP];   // 56 KB staged window
  __shared__ u32 s_cnt[BKT];  // hist, then scatter cursors
  __shared__ u32 s_off[BKT];  // inclusive scan
  const int b = blockIdx.x;
  const u32 wbeg = (u32)b * (u32)CAP;
  u32 fill = bcur[b] - wbeg;
  if (fill > (u32)CAP) fill = (u32)CAP;

  for (u32 i = threadIdx.x; i < fill; i += 1024) s_pw[i] = pairs[wbeg + i];
  s_cnt[threadIdx.x] = 0;  // blockDim == BKT
  __syncthreads();
  for (u32 i = threadIdx.x; i < fill; i += 1024)
    atomicAdd(&s_cnt[s_pw[i] & (BKT - 1u)], 1u);
  __syncthreads();

  const u32 v = s_cnt[threadIdx.x];
  s_off[threadIdx.x] = v;
  __syncthreads();
  for (int d = 1; d < BKT; d <<= 1) {
    const u32 add = (threadIdx.x >= (unsigned)d) ? s_off[threadIdx.x - d] : 0u;
    __syncthreads();
    s_off[threadIdx.x] += add;
    __syncthreads();
  }
  const u32 excl = s_off[threadIdx.x] - v;

  const int t0 = b << BSH;
  if (t0 + (int)threadIdx.x < n_tgt)
    offsets[t0 + threadIdx.x] = (v << 16) | excl;  // cnt<<16 | local_beg

  s_cnt[threadIdx.x] = excl;  // scatter cursors
  __syncthreads();
  for (u32 i = threadIdx.x; i < fill; i += 1024) {
    const u32 pw = s_pw[i];
    const u32 loc = atomicAdd(&s_cnt[pw & (BKT - 1u)], 1u);
    pairs[wbeg + loc] = pw >> BSH;  // in-place CSR (cached store)
  }
}

__global__ __launch_bounds__(256) void gather_reduce_kernel(
    const float* __restrict__ feat, const u32* __restrict__ csr,
    const u32* __restrict__ offsets, float* __restrict__ out, int n_tgt) {
  const int tid = blockIdx.x * 256 + threadIdx.x;
  const int t = tid >> 3;
  const int g = tid & 7;
  if (t >= n_tgt) return;
  const u32 off = __builtin_nontemporal_load(&offsets[t]);
  const u32 n = off >> 16;
  const u32 base = ((u32)(t >> BSH)) * (u32)CAP + (off & 0xFFFFu);
  const int l4 = g * 4;

  f32x4 acc = {0.f, 0.f, 0.f, 0.f};
  for (u32 c = 0; c < n; c += 8) {
    const u32 m = n - c;  // >= 1
    u32 idx[8];
#pragma unroll
    for (int k = 0; k < 8; ++k)
      idx[k] = __builtin_nontemporal_load(
          &csr[base + c + ((u32)k < m ? (u32)k : 0u)]);
    f32x4 v[8];
#pragma unroll
    for (int k = 0; k < 8; ++k)
      v[k] = *reinterpret_cast<const f32x4*>(feat +
                                             (long long)idx[k] * CCH + l4);
#pragma unroll
    for (int k = 0; k < 8; ++k) {
      const float w = ((u32)k < m) ? 1.0f : 0.0f;
      acc += v[k] * w;
    }
  }
  const float inv = n ? 1.0f / (float)n : 0.0f;
  const f32x4 r = acc * inv;
  // full-line streaming store (64 lanes x 16B contiguous): nt is safe here
  __builtin_nontemporal_store(
      r, reinterpret_cast<f32x4*>(out + (long long)t * CCH + l4));
}

// ---------------- fallback: R1 atomic path ----------------

__global__ __launch_bounds__(256) void scatter_accum_kernel(
    const float* __restrict__ feat, const int* __restrict__ src_ids,
    const int* __restrict__ tgt_ids, const int* __restrict__ ntypes,
    float* __restrict__ sums, u32* __restrict__ counts,
    long long total_threads) {
  long long tid = (long long)blockIdx.x * blockDim.x + threadIdx.x;
  if (tid >= total_threads) return;
  const int e = (int)(tid >> 3);
  const int g = (int)(tid & 7);
  const long long eb = 3LL * e;
  if ((ntypes[eb] | ntypes[eb + 1] | ntypes[eb + 2]) < 0) return;
  const int s = src_ids[e];
  const int t = tgt_ids[e];
  const float4 v =
      *reinterpret_cast<const float4*>(feat + (long long)s * CCH + g * 4);
  float* dst = sums + (long long)t * CCH + g * 4;
  atomicAdd(dst + 0, v.x);
  atomicAdd(dst + 1, v.y);
  atomicAdd(dst + 2, v.z);
  atomicAdd(dst + 3, v.w);
  if (g == 0) atomicAdd(counts + t, 1u);
}

__global__ __launch_bounds__(256) void finalize_kernel(
    float* __restrict__ out, const u32* __restrict__ counts, int total_vec4) {
  int tid = blockIdx.x * blockDim.x + threadIdx.x;
  if (tid >= total_vec4) return;
  const int t = tid >> 3;
  const u32 cnt = counts[t];
  float4* p = reinterpret_cast<float4*>(out) + tid;
  float4 v = *p;
  const float inv = (cnt > 0u) ? (1.0f / (float)cnt) : 0.0f;
  v.x *= inv; v.y *= inv; v.z *= inv; v.w *= inv;
  *p = v;
}

// ---------------- launch ----------------

extern "C" void kernel_launch(void* const* d_in, const int* in_sizes, int n_in,
                              void* d_out, int out_size, void* d_ws,
                              size_t ws_size, hipStream_t stream) {
  const float* feat    = (const float*)d_in[0];
  const int*   src_ids = (const int*)d_in[1];
  const int*   tgt_ids = (const int*)d_in[2];
  const int*   ntypes  = (const int*)d_in[3];
  const int E     = in_sizes[1];
  const int n_src = in_sizes[0] / CCH;
  const int n_tgt = out_size / CCH;

  const int NB = (n_tgt + BKT - 1) >> BSH;

  // ws layout (u32): pairs/csr windows [NB*CAP] | bcur[NB] | offsets[n_tgt]
  const size_t need =
      ((size_t)NB * CAP + NB + (size_t)n_tgt) * sizeof(u32);
  const bool shapes_ok =
      NB <= 2048 && n_src <= (1 << 22) &&
      (long long)E <= (long long)NB * CAP * 3 / 4;  // fill margin

  if (ws_size >= need && shapes_ok) {
    u32* pairs   = (u32*)d_ws;
    u32* bcur    = pairs + (size_t)NB * CAP;
    u32* offsets = bcur + NB;

    init_bcur_kernel<<<(NB + 255) / 256, 256, 0, stream>>>(bcur, NB);
    const int bblocks = (E + BIN_TILE - 1) / BIN_TILE;
    bin_fixed_kernel<<<bblocks, 1024, 0, stream>>>(src_ids, tgt_ids, ntypes,
                                                   bcur, pairs, E, NB);
    csr_build_kernel<<<NB, 1024, 0, stream>>>(pairs, bcur, offsets, n_tgt);
    const long long gthreads = (long long)n_tgt * 8;
    const int gblocks = (int)((gthreads + 255) / 256);
    gather_reduce_kernel<<<gblocks, 256, 0, stream>>>(feat, pairs, offsets,
                                                      (float*)d_out, n_tgt);
  } else {
    float* sums   = (float*)d_out;
    u32*   counts = (u32*)d_ws;
    hipMemsetAsync(d_out, 0, (size_t)out_size * sizeof(float), stream);
    hipMemsetAsync(d_ws, 0, (size_t)n_tgt * sizeof(u32), stream);
    const long long total_threads = (long long)E * 8;
    const long long nblocks = (total_threads + 255) / 256;
    scatter_accum_kernel<<<(dim3)((unsigned int)nblocks), 256, 0, stream>>>(
        feat, src_ids, tgt_ids, ntypes, sums, counts, total_threads);
    const int total_vec4 = n_tgt * 8;
    finalize_kernel<<<(total_vec4 + 255) / 256, 256, 0, stream>>>(
        sums, counts, total_vec4);
  }
}

// Round 10
// 268.639 us; speedup vs baseline: 3.0112x; 1.0967x over previous
//
#include <hip/hip_runtime.h>

// Masked scatter-mean, 3-kernel pipeline (no float atomics anywhere).
// R10: csr_build fused into gather (block-per-bucket sort_gather): stage the
// bucket window in LDS, hist+scan+scatter in LDS, then register-accumulating
// gather reads indices from LDS. No csr HBM round-trip, no offsets array.
// nt hints only where proven safe (stream-once loads in bin/stage); gather's
// feat/out accesses are plain cached (R8/R9: nt hurt both directions).
//   init_bcur   : bcur[b] = b*CAP
//   bin_fixed   : ONE edge pass (nt loads); LDS hist; reserve ranges; plain
//                 cached scattered writes of packed (src<<10 | tgt&1023)
//   sort_gather : per-bucket LDS sort + predicated 8-deep register gather
// Fallback: R1 atomic path if ws too small / shapes out of range.

#define CCH 32
#define BSH 10            // 1024 targets per bucket
#define BKT 1024
#define CAP 8960          // slots per bucket window (mean fill ~7373, +18 sigma)
#define BIN_TILE 8192
typedef unsigned int u32;
typedef float f32x4 __attribute__((ext_vector_type(4)));

__global__ __launch_bounds__(256) void init_bcur_kernel(u32* __restrict__ bcur,
                                                        int NB) {
  int i = blockIdx.x * 256 + threadIdx.x;
  if (i < NB) bcur[i] = (u32)i * (u32)CAP;
}

__global__ __launch_bounds__(1024) void bin_fixed_kernel(
    const int* __restrict__ src_ids, const int* __restrict__ tgt_ids,
    const int* __restrict__ ntypes, u32* __restrict__ bcur,
    u32* __restrict__ pairs, int E, int NB) {
  __shared__ unsigned short s_b[BIN_TILE];  // bucket id (0xFFFF = invalid)
  __shared__ u32 s_pw[BIN_TILE];            // packed (src<<10 | local_tgt)
  __shared__ u32 s_cnt[2048];
  __shared__ u32 s_base[2048];
  const long long base = (long long)blockIdx.x * BIN_TILE;

  for (int j = threadIdx.x; j < 2048; j += 1024) s_cnt[j] = 0;
  __syncthreads();

  // merged load + histogram pass (nt loads: stream-once edge data)
  for (int k = 0; k < BIN_TILE / 1024; ++k) {
    const int i = threadIdx.x + k * 1024;
    const long long e = base + i;
    unsigned short bb = 0xFFFFu;
    u32 pw = 0;
    if (e < E) {
      const long long eb = 3LL * e;
      const int n0 = __builtin_nontemporal_load(&ntypes[eb]);
      const int n1 = __builtin_nontemporal_load(&ntypes[eb + 1]);
      const int n2 = __builtin_nontemporal_load(&ntypes[eb + 2]);
      if ((n0 | n1 | n2) >= 0) {
        const u32 t = (u32)__builtin_nontemporal_load(&tgt_ids[e]);
        const u32 s = (u32)__builtin_nontemporal_load(&src_ids[e]);
        bb = (unsigned short)(t >> BSH);
        pw = (s << BSH) | (t & (BKT - 1u));
        atomicAdd(&s_cnt[bb], 1u);
      }
    }
    s_b[i] = bb;
    s_pw[i] = pw;
  }
  __syncthreads();

  for (int j = threadIdx.x; j < NB; j += 1024) {
    const u32 c = s_cnt[j];
    s_base[j] = c ? atomicAdd(&bcur[j], c) : 0u;
    s_cnt[j] = 0;
  }
  __syncthreads();

  for (int k = 0; k < BIN_TILE / 1024; ++k) {
    const int i = threadIdx.x + k * 1024;
    const unsigned short bb = s_b[i];
    if (bb != 0xFFFFu) {
      const u32 loc = atomicAdd(&s_cnt[bb], 1u);
      const u32 slot = s_base[bb] + loc;
      if (slot < ((u32)bb + 1u) * (u32)CAP) pairs[slot] = s_pw[i];  // cached
    }
  }
}

// LDS: 35KB + 35KB + 4KB + 4KB = 78KB -> 2 blocks/CU (32 waves).
// __launch_bounds__(1024, 8): 8 waves/EU -> VGPR <= 64 so LDS stays the limit.
__global__ __launch_bounds__(1024, 8) void sort_gather_kernel(
    const float* __restrict__ feat, const u32* __restrict__ pairs,
    const u32* __restrict__ bcur, float* __restrict__ out, int n_tgt) {
  __shared__ u32 s_pw[CAP];   // staged window
  __shared__ u32 s_srt[CAP];  // src ids sorted by local target
  __shared__ u32 s_cnt[BKT];  // hist, then scatter cursors
  __shared__ u32 s_off[BKT];  // inclusive scan (preserved for gather)
  const int b = blockIdx.x;
  const u32 wbeg = (u32)b * (u32)CAP;
  u32 fill = bcur[b] - wbeg;
  if (fill > (u32)CAP) fill = (u32)CAP;

  for (u32 i = threadIdx.x; i < fill; i += 1024)
    s_pw[i] = __builtin_nontemporal_load(&pairs[wbeg + i]);  // stream-once
  s_cnt[threadIdx.x] = 0;  // blockDim == BKT
  __syncthreads();
  for (u32 i = threadIdx.x; i < fill; i += 1024)
    atomicAdd(&s_cnt[s_pw[i] & (BKT - 1u)], 1u);
  __syncthreads();

  const u32 v = s_cnt[threadIdx.x];
  s_off[threadIdx.x] = v;
  __syncthreads();
  for (int d = 1; d < BKT; d <<= 1) {
    const u32 add = (threadIdx.x >= (unsigned)d) ? s_off[threadIdx.x - d] : 0u;
    __syncthreads();
    s_off[threadIdx.x] += add;
    __syncthreads();
  }
  s_cnt[threadIdx.x] = s_off[threadIdx.x] - v;  // cursors = exclusive scan
  __syncthreads();
  for (u32 i = threadIdx.x; i < fill; i += 1024) {
    const u32 pw = s_pw[i];
    const u32 loc = atomicAdd(&s_cnt[pw & (BKT - 1u)], 1u);
    s_srt[loc] = pw >> BSH;
  }
  __syncthreads();

  const int grp = threadIdx.x >> 3;  // 0..127
  const int lane = threadIdx.x & 7;  // 4 channels each
  const int l4 = lane * 4;
  const long long t0 = (long long)b << BSH;
  for (int r = grp; r < BKT; r += 128) {
    const long long t = t0 + r;
    if (t >= n_tgt) break;
    const u32 beg = r ? s_off[r - 1] : 0u;
    const u32 n = s_off[r] - beg;
    f32x4 acc = {0.f, 0.f, 0.f, 0.f};
    for (u32 c = 0; c < n; c += 8) {
      const u32 m = n - c;  // >= 1
      u32 idx[8];
#pragma unroll
      for (int k = 0; k < 8; ++k)
        idx[k] = s_srt[beg + c + ((u32)k < m ? (u32)k : 0u)];
      f32x4 vv[8];
#pragma unroll
      for (int k = 0; k < 8; ++k)
        vv[k] = *reinterpret_cast<const f32x4*>(feat +
                                                (long long)idx[k] * CCH + l4);
#pragma unroll
      for (int k = 0; k < 8; ++k) {
        const float w = ((u32)k < m) ? 1.0f : 0.0f;
        acc += vv[k] * w;
      }
    }
    const float inv = n ? 1.0f / (float)n : 0.0f;
    acc *= inv;
    *reinterpret_cast<f32x4*>(out + t * CCH + l4) = acc;
  }
}

// ---------------- fallback: R1 atomic path ----------------

__global__ __launch_bounds__(256) void scatter_accum_kernel(
    const float* __restrict__ feat, const int* __restrict__ src_ids,
    const int* __restrict__ tgt_ids, const int* __restrict__ ntypes,
    float* __restrict__ sums, u32* __restrict__ counts,
    long long total_threads) {
  long long tid = (long long)blockIdx.x * blockDim.x + threadIdx.x;
  if (tid >= total_threads) return;
  const int e = (int)(tid >> 3);
  const int g = (int)(tid & 7);
  const long long eb = 3LL * e;
  if ((ntypes[eb] | ntypes[eb + 1] | ntypes[eb + 2]) < 0) return;
  const int s = src_ids[e];
  const int t = tgt_ids[e];
  const float4 v =
      *reinterpret_cast<const float4*>(feat + (long long)s * CCH + g * 4);
  float* dst = sums + (long long)t * CCH + g * 4;
  atomicAdd(dst + 0, v.x);
  atomicAdd(dst + 1, v.y);
  atomicAdd(dst + 2, v.z);
  atomicAdd(dst + 3, v.w);
  if (g == 0) atomicAdd(counts + t, 1u);
}

__global__ __launch_bounds__(256) void finalize_kernel(
    float* __restrict__ out, const u32* __restrict__ counts, int total_vec4) {
  int tid = blockIdx.x * blockDim.x + threadIdx.x;
  if (tid >= total_vec4) return;
  const int t = tid >> 3;
  const u32 cnt = counts[t];
  float4* p = reinterpret_cast<float4*>(out) + tid;
  float4 v = *p;
  const float inv = (cnt > 0u) ? (1.0f / (float)cnt) : 0.0f;
  v.x *= inv; v.y *= inv; v.z *= inv; v.w *= inv;
  *p = v;
}

// ---------------- launch ----------------

extern "C" void kernel_launch(void* const* d_in, const int* in_sizes, int n_in,
                              void* d_out, int out_size, void* d_ws,
                              size_t ws_size, hipStream_t stream) {
  const float* feat    = (const float*)d_in[0];
  const int*   src_ids = (const int*)d_in[1];
  const int*   tgt_ids = (const int*)d_in[2];
  const int*   ntypes  = (const int*)d_in[3];
  const int E     = in_sizes[1];
  const int n_src = in_sizes[0] / CCH;
  const int n_tgt = out_size / CCH;

  const int NB = (n_tgt + BKT - 1) >> BSH;

  // ws layout (u32): pairs windows [NB*CAP] | bcur[NB]
  const size_t need = ((size_t)NB * CAP + NB) * sizeof(u32);
  // per-bucket mean fill (unmasked upper bound) must leave sigma headroom
  const long long mean_fill = ((long long)E * BKT + n_tgt - 1) / n_tgt;
  const bool shapes_ok =
      NB <= 2048 && n_src <= (1 << 21) && mean_fill <= 8192;

  if (ws_size >= need && shapes_ok) {
    u32* pairs = (u32*)d_ws;
    u32* bcur  = pairs + (size_t)NB * CAP;

    init_bcur_kernel<<<(NB + 255) / 256, 256, 0, stream>>>(bcur, NB);
    const int bblocks = (E + BIN_TILE - 1) / BIN_TILE;
    bin_fixed_kernel<<<bblocks, 1024, 0, stream>>>(src_ids, tgt_ids, ntypes,
                                                   bcur, pairs, E, NB);
    sort_gather_kernel<<<NB, 1024, 0, stream>>>(feat, pairs, bcur,
                                                (float*)d_out, n_tgt);
  } else {
    float* sums   = (float*)d_out;
    u32*   counts = (u32*)d_ws;
    hipMemsetAsync(d_out, 0, (size_t)out_size * sizeof(float), stream);
    hipMemsetAsync(d_ws, 0, (size_t)n_tgt * sizeof(u32), stream);
    const long long total_threads = (long long)E * 8;
    const long long nblocks = (total_threads + 255) / 256;
    scatter_accum_kernel<<<(dim3)((unsigned int)nblocks), 256, 0, stream>>>(
        feat, src_ids, tgt_ids, ntypes, sums, counts, total_threads);
    const int total_vec4 = n_tgt * 8;
    finalize_kernel<<<(total_vec4 + 255) / 256, 256, 0, stream>>>(
        sums, counts, total_vec4);
  }
}